// Round 1
// baseline (1337.061 us; speedup 1.0000x reference)
//
#include <hip/hip_runtime.h>

#define DD 4096
#define BB 16
#define HH 32
#define HDD 128
#define TT 2048

// ---------------- Kernel 1: RMSNorm, writes xn transposed [D][B] ----------------
__global__ __launch_bounds__(256) void rmsnorm_k(const float* __restrict__ x,
                                                 const float* __restrict__ ln_w,
                                                 float* __restrict__ xnT) {
  const int b = blockIdx.x;
  const int tid = threadIdx.x;
  const float* xr = x + (size_t)b * DD;
  float4 v[4];
  float ss = 0.f;
#pragma unroll
  for (int i = 0; i < 4; ++i) {
    v[i] = ((const float4*)xr)[tid + i * 256];
    ss += v[i].x * v[i].x + v[i].y * v[i].y + v[i].z * v[i].z + v[i].w * v[i].w;
  }
#pragma unroll
  for (int off = 32; off; off >>= 1) ss += __shfl_xor(ss, off, 64);
  __shared__ float red[4];
  if ((tid & 63) == 0) red[tid >> 6] = ss;
  __syncthreads();
  float tot = red[0] + red[1] + red[2] + red[3];
  float rms = rsqrtf(tot / (float)DD + 1e-6f);
#pragma unroll
  for (int i = 0; i < 4; ++i) {
    int e = 4 * (tid + i * 256);
    float4 w4 = ((const float4*)ln_w)[tid + i * 256];
    xnT[(size_t)(e + 0) * BB + b] = v[i].x * rms * w4.x;
    xnT[(size_t)(e + 1) * BB + b] = v[i].y * rms * w4.y;
    xnT[(size_t)(e + 2) * BB + b] = v[i].z * rms * w4.z;
    xnT[(size_t)(e + 3) * BB + b] = v[i].w * rms * w4.w;
  }
}

// ------------- Kernel 2: QKV GEMV (M=16), split-K with atomic finalize -------------
// grid: (colchunk 16, kchunk 16, weight 3), block 256. Each thread: 1 col, 16 batches.
__global__ __launch_bounds__(256) void qkv_k(const float* __restrict__ xnT,
                                             const float* __restrict__ Wq,
                                             const float* __restrict__ Wk,
                                             const float* __restrict__ Wv,
                                             float* __restrict__ q,
                                             float* __restrict__ kn,
                                             float* __restrict__ vn) {
  const int col = blockIdx.x * 256 + threadIdx.x;
  const int k0 = blockIdx.y * 256;
  const float* W = blockIdx.z == 0 ? Wq : (blockIdx.z == 1 ? Wk : Wv);
  float* out = blockIdx.z == 0 ? q : (blockIdx.z == 1 ? kn : vn);
  float acc[BB];
#pragma unroll
  for (int b = 0; b < BB; ++b) acc[b] = 0.f;
  const float* Wp = W + (size_t)k0 * DD + col;
  const float* xp = xnT + (size_t)k0 * BB;  // wave-uniform reads -> scalar loads
  for (int k = 0; k < 256; k += 2) {
    float wv0 = Wp[(size_t)k * DD];
    float wv1 = Wp[(size_t)(k + 1) * DD];
#pragma unroll
    for (int b = 0; b < BB; ++b) acc[b] = fmaf(xp[k * BB + b], wv0, acc[b]);
#pragma unroll
    for (int b = 0; b < BB; ++b) acc[b] = fmaf(xp[(k + 1) * BB + b], wv1, acc[b]);
  }
#pragma unroll
  for (int b = 0; b < BB; ++b) atomicAdd(&out[(size_t)b * DD + col], acc[b]);
}

// ---------------- Kernel 3: ragged decode attention, one block per (b,h) ----------------
__global__ __launch_bounds__(256) void attn_k(const float* __restrict__ q,
                                              const float* __restrict__ kn,
                                              const float* __restrict__ vn,
                                              const float* __restrict__ Kc,
                                              const float* __restrict__ Vc,
                                              const int* __restrict__ lens,
                                              float* __restrict__ attnT) {
  const int h = blockIdx.x, b = blockIdx.y;
  const int tid = threadIdx.x;
  const int wave = tid >> 6, lane = tid & 63;
  const int L = lens[b];  // valid positions: t in [0, L]; t == L uses new k/v
  __shared__ float s_p[TT];
  __shared__ float s_redm[4], s_reds[4];
  __shared__ float s_o[256];
  const float scale = 0.08838834764831845f;  // 1/sqrt(128)
  const float2 qf = ((const float2*)(q + (size_t)b * DD + (size_t)h * HDD))[lane];
  const float* Kbase = Kc + (((size_t)b * TT) * HH + h) * HDD;
  float wmax = -3e38f;
  // Phase 1: scores. wave w handles t = w + 4j blocks, x4 unrolled for MLP.
  for (int t0 = wave * 4; t0 < L; t0 += 16) {
    float d[4] = {0.f, 0.f, 0.f, 0.f};
#pragma unroll
    for (int j = 0; j < 4; ++j) {
      int t = t0 + j;
      if (t < L) {
        float2 kf = ((const float2*)(Kbase + (size_t)t * (HH * HDD)))[lane];
        d[j] = qf.x * kf.x + qf.y * kf.y;
      }
    }
#pragma unroll
    for (int j = 0; j < 4; ++j) {
#pragma unroll
      for (int off = 32; off; off >>= 1) d[j] += __shfl_xor(d[j], off, 64);
      int t = t0 + j;
      if (t < L) {
        float sc = d[j] * scale;
        if (lane == 0) s_p[t] = sc;
        wmax = fmaxf(wmax, sc);
      }
    }
  }
  if (wave == 0) {  // new token at t == L
    float2 kf = ((const float2*)(kn + (size_t)b * DD + (size_t)h * HDD))[lane];
    float dnew = qf.x * kf.x + qf.y * kf.y;
#pragma unroll
    for (int off = 32; off; off >>= 1) dnew += __shfl_xor(dnew, off, 64);
    float sc = dnew * scale;
    if (lane == 0) s_p[L] = sc;
    wmax = fmaxf(wmax, sc);
  }
  if (lane == 0) s_redm[wave] = wmax;
  __syncthreads();
  const float m = fmaxf(fmaxf(s_redm[0], s_redm[1]), fmaxf(s_redm[2], s_redm[3]));
  // Phase 2: exp + sum
  float lsum = 0.f;
  for (int t = tid; t <= L; t += 256) {
    float e = __expf(s_p[t] - m);
    s_p[t] = e;
    lsum += e;
  }
#pragma unroll
  for (int off = 32; off; off >>= 1) lsum += __shfl_xor(lsum, off, 64);
  if (lane == 0) s_reds[wave] = lsum;
  __syncthreads();
  const float inv = 1.f / (s_reds[0] + s_reds[1] + s_reds[2] + s_reds[3]);
  // Phase 3: PV. Half-blocks stride t by 2; dim-parallel coalesced V reads.
  const int tt = tid >> 7, dd = tid & 127;
  const float* Vbase = Vc + (((size_t)b * TT) * HH + h) * HDD + dd;
  float o = 0.f;
  int t = tt;
  for (; t + 6 < L; t += 8) {
    float p0 = s_p[t], p1 = s_p[t + 2], p2 = s_p[t + 4], p3 = s_p[t + 6];
    const float* vb = Vbase + (size_t)t * (HH * HDD);
    o = fmaf(p0, vb[0], o);
    o = fmaf(p1, vb[2 * HH * HDD], o);
    o = fmaf(p2, vb[4 * HH * HDD], o);
    o = fmaf(p3, vb[6 * HH * HDD], o);
  }
  for (; t < L; t += 2) o = fmaf(s_p[t], Vbase[(size_t)t * (HH * HDD)], o);
  if (tt == 0) o = fmaf(s_p[L], vn[(size_t)b * DD + (size_t)h * HDD + dd], o);
  s_o[tid] = o;
  __syncthreads();
  if (tid < 128) {
    float val = (s_o[tid] + s_o[tid + 128]) * inv;
    attnT[(size_t)((size_t)h * HDD + tid) * BB + b] = val;  // transposed for o-proj
  }
}

// ------------- Kernel 4: O-proj GEMV + residual (d_out pre-init = x) -------------
__global__ __launch_bounds__(256) void oproj_k(const float* __restrict__ attnT,
                                               const float* __restrict__ Wo,
                                               float* __restrict__ out) {
  const int col = blockIdx.x * 256 + threadIdx.x;
  const int k0 = blockIdx.y * 256;
  float acc[BB];
#pragma unroll
  for (int b = 0; b < BB; ++b) acc[b] = 0.f;
  const float* Wp = Wo + (size_t)k0 * DD + col;
  const float* xp = attnT + (size_t)k0 * BB;
  for (int k = 0; k < 256; k += 2) {
    float wv0 = Wp[(size_t)k * DD];
    float wv1 = Wp[(size_t)(k + 1) * DD];
#pragma unroll
    for (int b = 0; b < BB; ++b) acc[b] = fmaf(xp[k * BB + b], wv0, acc[b]);
#pragma unroll
    for (int b = 0; b < BB; ++b) acc[b] = fmaf(xp[(k + 1) * BB + b], wv1, acc[b]);
  }
#pragma unroll
  for (int b = 0; b < BB; ++b) atomicAdd(&out[(size_t)b * DD + col], acc[b]);
}

extern "C" void kernel_launch(void* const* d_in, const int* in_sizes, int n_in,
                              void* d_out, int out_size, void* d_ws, size_t ws_size,
                              hipStream_t stream) {
  const float* x    = (const float*)d_in[0];
  const float* ln_w = (const float*)d_in[1];
  const float* Wq   = (const float*)d_in[2];
  const float* Wk   = (const float*)d_in[3];
  const float* Wv   = (const float*)d_in[4];
  const float* Wo   = (const float*)d_in[5];
  const float* Kc   = (const float*)d_in[6];
  const float* Vc   = (const float*)d_in[7];
  const int*   lens = (const int*)d_in[8];

  float* ws    = (float*)d_ws;
  float* xnT   = ws;                 // 65536 floats  [D][B]
  float* q     = ws + 1 * 65536;     // [B][D]
  float* kn    = ws + 2 * 65536;     // [B][D]
  float* vn    = ws + 3 * 65536;     // [B][D]
  float* attnT = ws + 4 * 65536;     // [D][B]
  float* out   = (float*)d_out;

  // zero q/kn/vn (atomic-accumulated); residual-init d_out = x
  hipMemsetAsync(q, 0, 3 * 65536 * sizeof(float), stream);
  hipMemcpyAsync(out, x, 65536 * sizeof(float), hipMemcpyDeviceToDevice, stream);

  rmsnorm_k<<<16, 256, 0, stream>>>(x, ln_w, xnT);
  qkv_k<<<dim3(16, 16, 3), 256, 0, stream>>>(xnT, Wq, Wk, Wv, q, kn, vn);
  attn_k<<<dim3(32, 16), 256, 0, stream>>>(q, kn, vn, Kc, Vc, lens, attnT);
  oproj_k<<<dim3(16, 16), 256, 0, stream>>>(attnT, Wo, out);
}